// Round 1
// baseline (933.304 us; speedup 1.0000x reference)
//
#include <hip/hip_runtime.h>
#include <stdint.h>

typedef unsigned short u16;
typedef __bf16 bf16x8 __attribute__((ext_vector_type(8)));
typedef float  f32x4  __attribute__((ext_vector_type(4)));

#define D_MODEL 2048
#define SEQ     4096
#define NROWS   16384     // B*S = 4*4096
#define THREE_D 6144
#define K_SIZE  4
#define KC      2048      // GEMM K (both GEMMs)
#define NT      64        // K-steps of 32

__device__ __forceinline__ float b2f(u16 u) {
    union { uint32_t i; float f; } v; v.i = ((uint32_t)u) << 16; return v.f;
}
__device__ __forceinline__ u16 f2b(float f) {
    uint32_t u = __builtin_bit_cast(uint32_t, f);
    u += 0x7fff + ((u >> 16) & 1);          // RNE
    return (u16)(u >> 16);
}

// ---------------- fp32 -> bf16 cast (8 elems/thread) ----------------
__global__ __launch_bounds__(256) void cast_f32_to_bf16(
    const float* __restrict__ src, u16* __restrict__ dst, int n8)
{
    int i = blockIdx.x * blockDim.x + threadIdx.x;
    if (i >= n8) return;
    const float4* s = (const float4*)src + (size_t)i * 2;
    float4 a = s[0], b = s[1];
    union { u16 u[8]; uint4 v; } o;
    o.u[0] = f2b(a.x); o.u[1] = f2b(a.y); o.u[2] = f2b(a.z); o.u[3] = f2b(a.w);
    o.u[4] = f2b(b.x); o.u[5] = f2b(b.y); o.u[6] = f2b(b.z); o.u[7] = f2b(b.w);
    *(uint4*)(dst + (size_t)i * 8) = o.v;
}

// ---------------- conv_w [D,1,K] -> cwt [K,D] transpose ----------------
__global__ __launch_bounds__(256) void prep_cwt(
    const float* __restrict__ cw, float* __restrict__ cwt)
{
    int i = blockIdx.x * blockDim.x + threadIdx.x;
    if (i >= D_MODEL * K_SIZE) return;
    int d = i >> 2, k = i & 3;
    cwt[k * D_MODEL + d] = cw[i];
}

#define GLDS(gp, lp) __builtin_amdgcn_global_load_lds( \
    (const __attribute__((address_space(1))) void*)(gp), \
    (__attribute__((address_space(3))) void*)(lp), 16, 0, 0)

// ---------------- bf16 NT GEMM: C[M,N] = A[M,K] * B[N,K]^T ----------------
// 256x256 tile, BK=32, 512 threads = 8 waves (2M x 4N), each wave 128x64 out
// (acc[8][4] of 16x16x32 MFMA). Deep pipeline, T3+T4+T5:
//   - LDS ring of 4 K-step buffers (32 KiB each: A 16K + B 16K) = 128 KiB.
//     Phase t: compute from buf[t&3], stage K-step t+3 into buf[(t+3)&3].
//     Live set {t..t+3} distinct mod 4 -> staging never lands in a buffer any
//     wave can be reading: race-free with loads in flight across barriers.
//   - Counted vmcnt(8) per phase (2 tiles = 8 loads/wave outstanding; tile
//     t+1 guaranteed landed). Never vmcnt(0) in the main loop. Raw s_barrier,
//     no __syncthreads() drain.
//   - Fragment-major LDS layout: 16B chunk (g,fq,fr) at u16 off
//     g*512 + fq*128 + fr*8 holds A[g*16+fr][fq*8..+7]. Staging dest is
//     lane-linear (wave-uniform base + lane*16); the *global* source address
//     is permuted to match (rule 21). ds_read_b128 fragment reads hit the
//     uniform 8-lanes-per-16B-slot minimum -> conflict-free.
//   - s_setprio(1) around the 32-MFMA cluster.
// Grid 1D, xcd = idx&7 N-slicing as before (grids are multiples of 8).
template<int BF16OUT>
__global__ __launch_bounds__(512, 2) void gemm256(
    const u16* __restrict__ A, const u16* __restrict__ B,
    void* __restrict__ Cout, int N, int n_per_xcd)
{
    __shared__ __align__(16) u16 lds[65536];   // 4 bufs x (A 8192 + B 8192) u16

    const int tid  = threadIdx.x;
    const int lane = tid & 63;
    const int wave = tid >> 6;

    const int idx   = blockIdx.x;
    const int xcd   = idx & 7;
    const int local = idx >> 3;
    const int bm  = local / n_per_xcd;
    const int bn  = xcd * n_per_xcd + (local - bm * n_per_xcd);

    // staging: chunk index (pass p in {0,1}) = p*512 + tid;
    // fr = idx&15, fq = (idx>>4)&3, g = idx>>6  -> row = g*16+fr, colchunk = fq
    const int sfr  = tid & 15;
    const int sfq  = (tid >> 4) & 3;
    const int srow = (tid >> 6) * 16 + sfr;       // pass0 row 0..127; pass1 +128
    const size_t sK = (size_t)KC;
    const u16* ga = A + ((size_t)(bm * 256) + srow) * sK + sfq * 8;
    const u16* gb = B + ((size_t)(bn * 256) + srow) * sK + sfq * 8;

    u16* dst0 = lds + wave * 512;   // + buf*16384; +4096 pass1; +8192 B region

    // fragment read addressing
    const int fr = lane & 15;
    const int fq = lane >> 4;
    const int wm = (wave >> 2) * 128;
    const int wn = (wave & 3) * 64;
    const int aBase = (wave >> 2) * 4096 + fq * 128 + fr * 8;          // g-offset 8*512
    const int bBase = 8192 + (wave & 3) * 2048 + fq * 128 + fr * 8;    // g-offset 4*512

    f32x4 acc[8][4] = {};

    // prologue: stage K-steps 0,1,2 (order pinned so vmcnt counts whole tiles)
    #pragma unroll
    for (int t = 0; t < 3; t++) {
        u16* d = dst0 + t * 16384;
        const int kk = t * 32;
        GLDS(ga + kk,            d);
        GLDS(ga + 128 * sK + kk, d + 4096);
        GLDS(gb + kk,            d + 8192);
        GLDS(gb + 128 * sK + kk, d + 12288);
        __builtin_amdgcn_sched_barrier(0);
    }
    asm volatile("s_waitcnt vmcnt(8)" ::: "memory");   // tile 0 landed
    __builtin_amdgcn_s_barrier();
    __builtin_amdgcn_sched_barrier(0);

    for (int t = 0; t < NT; t++) {
        const int buf = t & 3;
        if (t + 3 < NT) {                               // stage K-step t+3
            u16* d = dst0 + ((t + 3) & 3) * 16384;
            const int kk = (t + 3) * 32;
            GLDS(ga + kk,            d);
            GLDS(ga + 128 * sK + kk, d + 4096);
            GLDS(gb + kk,            d + 8192);
            GLDS(gb + 128 * sK + kk, d + 12288);
        }
        __builtin_amdgcn_sched_barrier(0);

        bf16x8 a[8], b[4];
        const u16* la = lds + buf * 16384 + aBase;
        const u16* lb = lds + buf * 16384 + bBase;
        #pragma unroll
        for (int i = 0; i < 8; i++) a[i] = *(const bf16x8*)(la + i * 512);
        #pragma unroll
        for (int j = 0; j < 4; j++) b[j] = *(const bf16x8*)(lb + j * 512);

        __builtin_amdgcn_s_setprio(1);
        #pragma unroll
        for (int i = 0; i < 8; i++)
            #pragma unroll
            for (int j = 0; j < 4; j++)
                acc[i][j] = __builtin_amdgcn_mfma_f32_16x16x32_bf16(
                    a[i], b[j], acc[i][j], 0, 0, 0);
        __builtin_amdgcn_s_setprio(0);

        // phase end: ds_reads consumed; keep 2 tiles of loads in flight
        asm volatile("s_waitcnt lgkmcnt(0)" ::: "memory");
        __builtin_amdgcn_sched_barrier(0);
        if (t < NT - 3) {
            asm volatile("s_waitcnt vmcnt(8)" ::: "memory");   // t+1 landed
        } else if (t == NT - 3) {
            asm volatile("s_waitcnt vmcnt(4)" ::: "memory");
        } else if (t == NT - 2) {
            asm volatile("s_waitcnt vmcnt(0)" ::: "memory");
        }
        __builtin_amdgcn_s_barrier();
        __builtin_amdgcn_sched_barrier(0);
    }

    // epilogue: D[m][n] -> col = lane&15, row = (lane>>4)*4 + reg  [m89-verified]
    const int row0 = bm * 256 + wm + fq * 4;
    const int col0 = bn * 256 + wn + fr;
    if (BF16OUT) {
        u16* C = (u16*)Cout;
        #pragma unroll
        for (int i = 0; i < 8; i++)
            #pragma unroll
            for (int j = 0; j < 4; j++)
                #pragma unroll
                for (int r = 0; r < 4; r++)
                    C[(size_t)(row0 + i * 16 + r) * N + (col0 + j * 16)] = f2b(acc[i][j][r]);
    } else {
        float* C = (float*)Cout;
        #pragma unroll
        for (int i = 0; i < 8; i++)
            #pragma unroll
            for (int j = 0; j < 4; j++)
                #pragma unroll
                for (int r = 0; r < 4; r++)
                    C[(size_t)(row0 + i * 16 + r) * N + (col0 + j * 16)] = acc[i][j][r];
    }
}

// ---------------- gate + causal depthwise conv + gate2 ----------------
// z[n,d] = Cg[n,d] * sum_{k=0..3} Bg[n-3+k,d]*Xg[n-3+k,d]*cw[d,k]
// BCx row layout: [Bg(0..2047) | Cg(2048..4095) | Xg(4096..6143)]
__global__ __launch_bounds__(256) void gate_conv(
    const u16* __restrict__ BCx, const float* __restrict__ cwt, u16* __restrict__ z)
{
    const int n  = blockIdx.x;              // 0..16383
    const int dg = threadIdx.x << 3;        // 8 channels per thread
    const int s  = n & (SEQ - 1);
    const u16* base = BCx + (size_t)n * THREE_D;

    float conv[8];
    #pragma unroll
    for (int j = 0; j < 8; j++) conv[j] = 0.f;

    #pragma unroll
    for (int r = 0; r < 4; r++) {           // tap index k = r, source row n-3+r
        const int back = 3 - r;
        if (s >= back) {                    // block-uniform branch
            const u16* pb = base - (size_t)back * THREE_D + dg;
            union { uint4 v; u16 u[8]; } ub, ux;
            ub.v = *(const uint4*)pb;                    // Bg
            ux.v = *(const uint4*)(pb + 2 * D_MODEL);    // Xg
            const float* w = cwt + r * D_MODEL + dg;
            float4 w0 = *(const float4*)w;
            float4 w1 = *(const float4*)(w + 4);
            float ww[8] = { w0.x, w0.y, w0.z, w0.w, w1.x, w1.y, w1.z, w1.w };
            #pragma unroll
            for (int j = 0; j < 8; j++)
                conv[j] += b2f(ub.u[j]) * b2f(ux.u[j]) * ww[j];
        }
    }

    union { uint4 v; u16 u[8]; } uc, uo;
    uc.v = *(const uint4*)(base + D_MODEL + dg);         // Cg
    #pragma unroll
    for (int j = 0; j < 8; j++)
        uo.u[j] = f2b(b2f(uc.u[j]) * conv[j]);
    *(uint4*)(z + (size_t)n * D_MODEL + dg) = uo.v;
}

extern "C" void kernel_launch(void* const* d_in, const int* in_sizes, int n_in,
                              void* d_out, int out_size, void* d_ws, size_t ws_size,
                              hipStream_t stream) {
    const float* x  = (const float*)d_in[0];   // [4,4096,2048]
    const float* w1 = (const float*)d_in[1];   // [6144,2048]
    const float* w2 = (const float*)d_in[2];   // [2048,2048]
    const float* cw = (const float*)d_in[3];   // [2048,1,4]
    float* out = (float*)d_out;                // [4,4096,2048] fp32

    // workspace layout (bytes), all 16B-aligned:
    char* ws = (char*)d_ws;
    u16*   xb  = (u16*)(ws);                       //  64 MiB  bf16 x
    u16*   w1b = (u16*)(ws + 67108864);            //  24 MiB  bf16 w1
    u16*   w2b = (u16*)(ws + 92274688);            //   8 MiB  bf16 w2
    float* cwt = (float*)(ws + 100663296);         //  32 KiB  conv_w transposed [K,D]
    u16*   bcx = (u16*)(ws + 100696064);           // 192 MiB  BCx bf16 [16384,6144]
    u16*   z   = (u16*)(ws + 302022656);           //  64 MiB  z bf16 [16384,2048]

    cast_f32_to_bf16<<<dim3((4194304 + 255) / 256), 256, 0, stream>>>(x,  xb,  4194304);
    cast_f32_to_bf16<<<dim3((1572864 + 255) / 256), 256, 0, stream>>>(w1, w1b, 1572864);
    cast_f32_to_bf16<<<dim3((524288  + 255) / 256), 256, 0, stream>>>(w2, w2b, 524288);
    prep_cwt<<<dim3(32), 256, 0, stream>>>(cw, cwt);

    // GEMM1: BCx = x @ w1^T   [16384,6144]; 64x24 tiles = 1536 blocks (3 N-tiles/XCD)
    gemm256<1><<<dim3(1536), 512, 0, stream>>>(xb, w1b, (void*)bcx, THREE_D, 3);
    // gate + conv -> z bf16 [16384,2048]
    gate_conv<<<dim3(NROWS), 256, 0, stream>>>(bcx, cwt, z);
    // GEMM2: out = z @ w2^T   [16384,2048] fp32; 64x8 tiles = 512 blocks (1 N-tile/XCD)
    gemm256<0><<<dim3(512), 512, 0, stream>>>(z, w2b, (void*)out, D_MODEL, 1);
}

// Round 2
// 904.728 us; speedup vs baseline: 1.0316x; 1.0316x over previous
//
#include <hip/hip_runtime.h>
#include <stdint.h>

typedef unsigned short u16;
typedef __bf16 bf16x8 __attribute__((ext_vector_type(8)));
typedef float  f32x4  __attribute__((ext_vector_type(4)));

#define D_MODEL 2048
#define SEQ     4096
#define NROWS   16384     // B*S = 4*4096
#define THREE_D 6144
#define K_SIZE  4
#define KC      2048      // GEMM K (both GEMMs)
#define NK      32        // K-tiles of 64

__device__ __forceinline__ float b2f(u16 u) {
    union { uint32_t i; float f; } v; v.i = ((uint32_t)u) << 16; return v.f;
}
__device__ __forceinline__ u16 f2b(float f) {
    uint32_t u = __builtin_bit_cast(uint32_t, f);
    u += 0x7fff + ((u >> 16) & 1);          // RNE
    return (u16)(u >> 16);
}

// ---------------- fp32 -> bf16 cast (8 elems/thread) ----------------
__global__ __launch_bounds__(256) void cast_f32_to_bf16(
    const float* __restrict__ src, u16* __restrict__ dst, int n8)
{
    int i = blockIdx.x * blockDim.x + threadIdx.x;
    if (i >= n8) return;
    const float4* s = (const float4*)src + (size_t)i * 2;
    float4 a = s[0], b = s[1];
    union { u16 u[8]; uint4 v; } o;
    o.u[0] = f2b(a.x); o.u[1] = f2b(a.y); o.u[2] = f2b(a.z); o.u[3] = f2b(a.w);
    o.u[4] = f2b(b.x); o.u[5] = f2b(b.y); o.u[6] = f2b(b.z); o.u[7] = f2b(b.w);
    *(uint4*)(dst + (size_t)i * 8) = o.v;
}

// ---------------- conv_w [D,1,K] -> cwt [K,D] transpose ----------------
__global__ __launch_bounds__(256) void prep_cwt(
    const float* __restrict__ cw, float* __restrict__ cwt)
{
    int i = blockIdx.x * blockDim.x + threadIdx.x;
    if (i >= D_MODEL * K_SIZE) return;
    int d = i >> 2, k = i & 3;
    cwt[k * D_MODEL + d] = cw[i];
}

#define GLDS(gp, lp) __builtin_amdgcn_global_load_lds( \
    (const __attribute__((address_space(1))) void*)(gp), \
    (__attribute__((address_space(3))) void*)(lp), 16, 0, 0)

// ---------------- bf16 NT GEMM: C[M,N] = A[M,K] * B[N,K]^T ----------------
// 256x256 tile, BK=64 (K-tile), 512 thr = 8 waves (2M x 4N), wave out 128x64.
// m201-style 4-phase-per-K-tile schedule (T2-free layout is conflict-free by
// construction; T3+T4+T5):
//   Zigzag quadrants (mh,nh): P1(0,0) P2(0,1) P3(1,1) P4(1,0).
//   Phase = {ds_read this quadrant's new frags (4/8/12 x b128)
//            || stage ONE half-tile (2 x global_load_lds)}
//           -> s_barrier -> lgkmcnt(0) -> 16 MFMA (setprio) -> s_barrier.
//   Half-tile regions & death: h0=A-even-quarters (dead after P1 reads),
//   h1=B-odd-32col-groups (P2), h2=A-odd-quarters (P3), h3=B-even (P4).
//   Stage schedule at iter kt: P1->(kt+1,h3)[other buf], P2->(kt+2,h0),
//   P3->(kt+2,h1), P4->(kt+2,h2) [same buf, region died the phase before;
//   barrier pair separates last read from write issue -> race-free].
//   vmcnt(6) ONCE per K-tile at P4 (3 half-tiles = 6 loads in flight);
//   never 0 in steady state. Prologue stages 7 half-tiles, vmcnt(6).
// LDS 128 KiB: 2 bufs x (A 32K + B 32K); chunk (ks,g,fq,fr) at u16 offset
//   ks*8192 + g*512 + fq*128 + fr*8 holding row g*16+fr, cols ks*32+fq*8..+7.
//   Staging dest is lane-linear (base + lane*16B); ds_read_b128 frag reads
//   touch 64 distinct 16B slots in 1024B -> conflict-free (verified r1: 0).
template<int BF16OUT>
__global__ __launch_bounds__(512, 2) void gemm256(
    const u16* __restrict__ A, const u16* __restrict__ B,
    void* __restrict__ Cout, int N, int n_per_xcd)
{
    __shared__ __align__(16) u16 lds[65536];   // 128 KiB

    const int tid  = threadIdx.x;
    const int lane = tid & 63;
    const int wv   = tid >> 6;

    const int idx   = blockIdx.x;
    const int xcd   = idx & 7;
    const int local = idx >> 3;
    const int bm  = local / n_per_xcd;
    const int bn  = xcd * n_per_xcd + (local - bm * n_per_xcd);

    // ---- staging addressing ----
    const int sfr = tid & 15;
    const int sfq = (tid >> 4) & 3;
    const int gA0 = (wv & 3) + (wv >> 2) * 8;        // h0 g; +4 -> h2
    const int gB0 = (wv & 1) + ((wv >> 1) & 3) * 4;  // h3 g; +2 -> h1
    const size_t sK = (size_t)KC;
    const u16* Ab = A + ((size_t)(bm * 256) + sfr) * sK + sfq * 8;
    const u16* Bb = B + ((size_t)(bn * 256) + sfr) * sK + sfq * 8;

#define STAGE_A(g, b, k64) { \
    GLDS(Ab + (size_t)((g) * 16) * sK + (k64),      lds + (b) * 32768 +         (g) * 512 + lane * 8); \
    GLDS(Ab + (size_t)((g) * 16) * sK + (k64) + 32, lds + (b) * 32768 +  8192 + (g) * 512 + lane * 8); }
#define STAGE_B(g, b, k64) { \
    GLDS(Bb + (size_t)((g) * 16) * sK + (k64),      lds + (b) * 32768 + 16384 + (g) * 512 + lane * 8); \
    GLDS(Bb + (size_t)((g) * 16) * sK + (k64) + 32, lds + (b) * 32768 + 24576 + (g) * 512 + lane * 8); }

    // ---- fragment addressing ----
    const int fr = lane & 15;
    const int fq = lane >> 4;
    const int aOff = (wv >> 2) * 4096 + fq * 128 + fr * 8;            // + m*512 + ks*8192
    const int bOff = 16384 + (wv & 3) * 2048 + fq * 128 + fr * 8;     // + n*512 + ks*8192

    f32x4 acc[8][4] = {};
    bf16x8 af[4][2], bf[2][2];

#define LOAD_A(buf, mh) { \
    const u16* _p = lds + (buf) * 32768 + aOff + (mh) * 2048; \
    _Pragma("unroll") for (int m = 0; m < 4; m++) { \
        af[m][0] = *(const bf16x8*)(_p + m * 512); \
        af[m][1] = *(const bf16x8*)(_p + m * 512 + 8192); } }
#define LOAD_B(buf, nh) { \
    const u16* _p = lds + (buf) * 32768 + bOff + (nh) * 1024; \
    _Pragma("unroll") for (int n = 0; n < 2; n++) { \
        bf[n][0] = *(const bf16x8*)(_p + n * 512); \
        bf[n][1] = *(const bf16x8*)(_p + n * 512 + 8192); } }

#define MFMA_Q(mh, nh) { \
    __builtin_amdgcn_s_setprio(1); \
    _Pragma("unroll") for (int m = 0; m < 4; m++) \
    _Pragma("unroll") for (int n = 0; n < 2; n++) { \
        acc[(mh)*4+m][(nh)*2+n] = __builtin_amdgcn_mfma_f32_16x16x32_bf16( \
            af[m][0], bf[n][0], acc[(mh)*4+m][(nh)*2+n], 0, 0, 0); \
        acc[(mh)*4+m][(nh)*2+n] = __builtin_amdgcn_mfma_f32_16x16x32_bf16( \
            af[m][1], bf[n][1], acc[(mh)*4+m][(nh)*2+n], 0, 0, 0); } \
    __builtin_amdgcn_s_setprio(0); }

#define SYNC1 { __builtin_amdgcn_sched_barrier(0); __builtin_amdgcn_s_barrier(); \
    asm volatile("s_waitcnt lgkmcnt(0)" ::: "memory"); __builtin_amdgcn_sched_barrier(0); }
#define SYNC2 { __builtin_amdgcn_sched_barrier(0); __builtin_amdgcn_s_barrier(); \
    __builtin_amdgcn_sched_barrier(0); }

    // ---- prologue: k0 all 4 halves, then k1 h0..h2 (14 loads/wave) ----
    STAGE_A(gA0,     0, 0);     // k0 h0
    STAGE_B(gB0 + 2, 0, 0);     // k0 h1
    STAGE_A(gA0 + 4, 0, 0);     // k0 h2
    STAGE_B(gB0,     0, 0);     // k0 h3
    STAGE_A(gA0,     1, 64);    // k1 h0
    STAGE_B(gB0 + 2, 1, 64);    // k1 h1
    STAGE_A(gA0 + 4, 1, 64);    // k1 h2
    __builtin_amdgcn_sched_barrier(0);
    asm volatile("s_waitcnt vmcnt(6)" ::: "memory");   // k0 landed
    __builtin_amdgcn_s_barrier();
    __builtin_amdgcn_sched_barrier(0);

    for (int kt = 0; kt < NK; kt++) {
        const int buf = kt & 1, nbuf = buf ^ 1;
        const int k64 = kt * 64;

        // P1: quad (0,0) — 12 ds_reads; stage (kt+1, h3)
        LOAD_A(buf, 0); LOAD_B(buf, 0);
        if (kt + 1 < NK) STAGE_B(gB0, nbuf, k64 + 64);
        SYNC1; MFMA_Q(0, 0); SYNC2;

        // P2: quad (0,1) — 4 ds_reads; stage (kt+2, h0)
        LOAD_B(buf, 1);
        if (kt + 2 < NK) STAGE_A(gA0, buf, k64 + 128);
        SYNC1; MFMA_Q(0, 1); SYNC2;

        // P3: quad (1,1) — 8 ds_reads; stage (kt+2, h1)
        LOAD_A(buf, 1);
        if (kt + 2 < NK) STAGE_B(gB0 + 2, buf, k64 + 128);
        SYNC1; MFMA_Q(1, 1); SYNC2;

        // P4: quad (1,0) — 4 ds_reads (nh0 reload); stage (kt+2, h2); vmcnt
        LOAD_B(buf, 0);
        if (kt + 2 < NK) STAGE_A(gA0 + 4, buf, k64 + 128);
        __builtin_amdgcn_sched_barrier(0);
        if (kt < NK - 2) {
            asm volatile("s_waitcnt vmcnt(6)" ::: "memory");   // kt+1 landed
        } else if (kt == NK - 2) {
            asm volatile("s_waitcnt vmcnt(0)" ::: "memory");
        }
        SYNC1; MFMA_Q(1, 0); SYNC2;
    }

    // ---- epilogue: D[m][n] -> col = lane&15, row = (lane>>4)*4 + reg ----
    const int wm = (wv >> 2) * 128;
    const int wn = (wv & 3) * 64;
    const int row0 = bm * 256 + wm + fq * 4;
    const int col0 = bn * 256 + wn + fr;
    if (BF16OUT) {
        u16* C = (u16*)Cout;
        #pragma unroll
        for (int i = 0; i < 8; i++)
            #pragma unroll
            for (int j = 0; j < 4; j++)
                #pragma unroll
                for (int r = 0; r < 4; r++)
                    C[(size_t)(row0 + i * 16 + r) * N + (col0 + j * 16)] = f2b(acc[i][j][r]);
    } else {
        float* C = (float*)Cout;
        #pragma unroll
        for (int i = 0; i < 8; i++)
            #pragma unroll
            for (int j = 0; j < 4; j++)
                #pragma unroll
                for (int r = 0; r < 4; r++)
                    C[(size_t)(row0 + i * 16 + r) * N + (col0 + j * 16)] = acc[i][j][r];
    }
#undef STAGE_A
#undef STAGE_B
#undef LOAD_A
#undef LOAD_B
#undef MFMA_Q
#undef SYNC1
#undef SYNC2
}

// ---------------- gate + causal depthwise conv + gate2 ----------------
// z[n,d] = Cg[n,d] * sum_{k=0..3} Bg[n-3+k,d]*Xg[n-3+k,d]*cw[d,k]
// BCx row layout: [Bg(0..2047) | Cg(2048..4095) | Xg(4096..6143)]
__global__ __launch_bounds__(256) void gate_conv(
    const u16* __restrict__ BCx, const float* __restrict__ cwt, u16* __restrict__ z)
{
    const int n  = blockIdx.x;              // 0..16383
    const int dg = threadIdx.x << 3;        // 8 channels per thread
    const int s  = n & (SEQ - 1);
    const u16* base = BCx + (size_t)n * THREE_D;

    float conv[8];
    #pragma unroll
    for (int j = 0; j < 8; j++) conv[j] = 0.f;

    #pragma unroll
    for (int r = 0; r < 4; r++) {           // tap index k = r, source row n-3+r
        const int back = 3 - r;
        if (s >= back) {                    // block-uniform branch
            const u16* pb = base - (size_t)back * THREE_D + dg;
            union { uint4 v; u16 u[8]; } ub, ux;
            ub.v = *(const uint4*)pb;                    // Bg
            ux.v = *(const uint4*)(pb + 2 * D_MODEL);    // Xg
            const float* w = cwt + r * D_MODEL + dg;
            float4 w0 = *(const float4*)w;
            float4 w1 = *(const float4*)(w + 4);
            float ww[8] = { w0.x, w0.y, w0.z, w0.w, w1.x, w1.y, w1.z, w1.w };
            #pragma unroll
            for (int j = 0; j < 8; j++)
                conv[j] += b2f(ub.u[j]) * b2f(ux.u[j]) * ww[j];
        }
    }

    union { uint4 v; u16 u[8]; } uc, uo;
    uc.v = *(const uint4*)(base + D_MODEL + dg);         // Cg
    #pragma unroll
    for (int j = 0; j < 8; j++)
        uo.u[j] = f2b(b2f(uc.u[j]) * conv[j]);
    *(uint4*)(z + (size_t)n * D_MODEL + dg) = uo.v;
}

extern "C" void kernel_launch(void* const* d_in, const int* in_sizes, int n_in,
                              void* d_out, int out_size, void* d_ws, size_t ws_size,
                              hipStream_t stream) {
    const float* x  = (const float*)d_in[0];   // [4,4096,2048]
    const float* w1 = (const float*)d_in[1];   // [6144,2048]
    const float* w2 = (const float*)d_in[2];   // [2048,2048]
    const float* cw = (const float*)d_in[3];   // [2048,1,4]
    float* out = (float*)d_out;                // [4,4096,2048] fp32

    // workspace layout (bytes), all 16B-aligned:
    char* ws = (char*)d_ws;
    u16*   xb  = (u16*)(ws);                       //  64 MiB  bf16 x
    u16*   w1b = (u16*)(ws + 67108864);            //  24 MiB  bf16 w1
    u16*   w2b = (u16*)(ws + 92274688);            //   8 MiB  bf16 w2
    float* cwt = (float*)(ws + 100663296);         //  32 KiB  conv_w transposed [K,D]
    u16*   bcx = (u16*)(ws + 100696064);           // 192 MiB  BCx bf16 [16384,6144]
    u16*   z   = (u16*)(ws + 302022656);           //  64 MiB  z bf16 [16384,2048]

    cast_f32_to_bf16<<<dim3((4194304 + 255) / 256), 256, 0, stream>>>(x,  xb,  4194304);
    cast_f32_to_bf16<<<dim3((1572864 + 255) / 256), 256, 0, stream>>>(w1, w1b, 1572864);
    cast_f32_to_bf16<<<dim3((524288  + 255) / 256), 256, 0, stream>>>(w2, w2b, 524288);
    prep_cwt<<<dim3(32), 256, 0, stream>>>(cw, cwt);

    // GEMM1: BCx = x @ w1^T   [16384,6144]; 64x24 tiles = 1536 blocks (3 N-tiles/XCD)
    gemm256<1><<<dim3(1536), 512, 0, stream>>>(xb, w1b, (void*)bcx, THREE_D, 3);
    // gate + conv -> z bf16 [16384,2048]
    gate_conv<<<dim3(NROWS), 256, 0, stream>>>(bcx, cwt, z);
    // GEMM2: out = z @ w2^T   [16384,2048] fp32; 64x8 tiles = 512 blocks (1 N-tile/XCD)
    gemm256<0><<<dim3(512), 512, 0, stream>>>(z, w2b, (void*)out, D_MODEL, 1);
}